// Round 3
// baseline (202.516 us; speedup 1.0000x reference)
//
#include <hip/hip_runtime.h>
#include <hip/hip_cooperative_groups.h>

namespace cg = cooperative_groups;

#define SEG 64
#define TPB 256

struct DA { float d, a; };

__device__ __forceinline__ DA da_compose(DA f, DA g) {
    // apply f first, then g:  c -> (c*f.d + f.a)*g.d + g.a
    DA r; r.d = f.d * g.d; r.a = fmaf(f.a, g.d, g.a); return r;
}

// Single fused cooperative kernel:
//   stage 1: per-thread segment (D,A) + per-event decay factors e[] kept in VGPRs
//   stage 2: block-local exclusive scan (shuffle), block aggregate -> ws
//   grid.sync
//   stage 3: block 0 scans the block aggregates -> per-block carries + S(T)
//   grid.sync
//   stage 4: per-thread recurrence over register-resident e[]: S=fma(S,e,e),
//            lsum += log(fma(ab,S,mu)); deterministic per-block sums -> ws
//   grid.sync
//   stage 5: block 0 reduces block sums, assembles LL - integral -> out
__global__ void __launch_bounds__(TPB, 1) hawkes_fused(
    const float* __restrict__ ts,
    const float* __restrict__ mu_p, const float* __restrict__ la_p,
    const float* __restrict__ lb_p, const int* __restrict__ T_p,
    int N, int NSEG, int NB,
    DA* __restrict__ blkDA, float* __restrict__ blkCarry,
    double* __restrict__ blkSum, float* __restrict__ stats,
    float* __restrict__ out)
{
    cg::grid_group grid = cg::this_grid();
    const float beta  = __expf(*lb_p);
    const float mu    = *mu_p;
    const float alpha = __expf(*la_p);
    const float ab    = alpha * beta;
    const float Tf    = (float)(*T_p);
    const int tid  = threadIdx.x;
    const int g    = blockIdx.x * TPB + tid;
    const int lane = tid & 63, wave = tid >> 6;

    // ---------------- stage 1: segment (D,A); decay factors stay in registers ----
    float e[SEG];                 // e[k] = exp(-beta*(t_k - t_{k-1})), k=1..SEG-1
    DA my; my.d = 1.f; my.a = 0.f;
    bool full = false;
    const int start = g * SEG;
    const int end   = (g < NSEG) ? min(start + SEG, N) : start;
    if (g < NSEG) {
        full = (end == start + SEG);
        const float rnext = (end < N) ? ts[end] : Tf;
        float R = 1.f, t0, tprev;
        if (full) {
            const float4* p = (const float4*)(ts + start);
            float4 v = p[0];
            t0 = v.x;
            e[1] = __expf(-beta * (v.y - v.x));
            e[2] = __expf(-beta * (v.z - v.y));
            e[3] = __expf(-beta * (v.w - v.z));
            R = fmaf(R, e[1], 1.f); R = fmaf(R, e[2], 1.f); R = fmaf(R, e[3], 1.f);
            tprev = v.w;
            #pragma unroll
            for (int q = 1; q < SEG / 4; ++q) {
                float4 w4 = p[q];
                e[4*q+0] = __expf(-beta * (w4.x - tprev));
                e[4*q+1] = __expf(-beta * (w4.y - w4.x));
                e[4*q+2] = __expf(-beta * (w4.z - w4.y));
                e[4*q+3] = __expf(-beta * (w4.w - w4.z));
                R = fmaf(R, e[4*q+0], 1.f);
                R = fmaf(R, e[4*q+1], 1.f);
                R = fmaf(R, e[4*q+2], 1.f);
                R = fmaf(R, e[4*q+3], 1.f);
                tprev = w4.w;
            }
        } else {
            t0 = ts[start]; tprev = t0;
            for (int j = start + 1; j < end; ++j) {
                float t = ts[j];
                float ee = __expf(-beta * (t - tprev));
                R = fmaf(R, ee, 1.f); tprev = t;
            }
        }
        my.a = R * __expf(-beta * (rnext - tprev));
        my.d = __expf(-beta * (rnext - t0));
    }

    // ---------------- stage 2: block-local exclusive scan + aggregate -----------
    DA inc = my;
    #pragma unroll
    for (int off = 1; off < 64; off <<= 1) {
        DA up; up.d = __shfl_up(inc.d, off); up.a = __shfl_up(inc.a, off);
        if (lane >= off) inc = da_compose(up, inc);
    }
    __shared__ DA waveAgg[TPB / 64];
    if (lane == 63) waveAgg[wave] = inc;
    __syncthreads();
    DA pre; pre.d = 1.f; pre.a = 0.f;
    for (int w = 0; w < wave; ++w) pre = da_compose(pre, waveAgg[w]);
    DA lexcl; lexcl.d = __shfl_up(inc.d, 1); lexcl.a = __shfl_up(inc.a, 1);
    if (lane == 0) { lexcl.d = 1.f; lexcl.a = 0.f; }
    DA excl = da_compose(pre, lexcl);          // kept in registers for stage 4
    if (tid == TPB - 1) {
        DA agg = da_compose(pre, inc);         // pre covers waves<3; inc is wave 3 incl
        blkDA[blockIdx.x] = agg;
    }
    __threadfence();
    grid.sync();

    // ---------------- stage 3: block 0 scans block aggregates -------------------
    if (blockIdx.x == 0) {
        const int K2 = (NB + TPB - 1) / TPB;
        const int b0 = min(tid * K2, NB);
        const int b1 = min(b0 + K2, NB);
        DA comp; comp.d = 1.f; comp.a = 0.f;
        for (int b = b0; b < b1; ++b) comp = da_compose(comp, blkDA[b]);
        DA inc2 = comp;
        #pragma unroll
        for (int off = 1; off < 64; off <<= 1) {
            DA up; up.d = __shfl_up(inc2.d, off); up.a = __shfl_up(inc2.a, off);
            if (lane >= off) inc2 = da_compose(up, inc2);
        }
        __shared__ DA waveAgg2[TPB / 64];
        if (lane == 63) waveAgg2[wave] = inc2;
        __syncthreads();
        DA pre2; pre2.d = 1.f; pre2.a = 0.f;
        for (int w = 0; w < wave; ++w) pre2 = da_compose(pre2, waveAgg2[w]);
        DA lex2; lex2.d = __shfl_up(inc2.d, 1); lex2.a = __shfl_up(inc2.a, 1);
        if (lane == 0) { lex2.d = 1.f; lex2.a = 0.f; }
        DA ex2 = da_compose(pre2, lex2);
        float c = ex2.a;                       // global carry starts at 0
        for (int b = b0; b < b1; ++b) {
            blkCarry[b] = c;
            DA x = blkDA[b];
            c = fmaf(c, x.d, x.a);
        }
        if (b0 < NB && b1 == NB) stats[0] = c; // S(T)
        __threadfence();
    }
    grid.sync();

    // ---------------- stage 4: per-event intensities from register e[] ----------
    const float bc = blkCarry[blockIdx.x];
    float S = fmaf(bc, excl.d, excl.a);        // exclusive decayed sum at first event
    float lsum0 = 0.f, lsum1 = 0.f;
    if (g < NSEG) {
        if (full) {
            // event 0 at entry S
            lsum0 += __logf(fmaf(ab, S, mu));
            // events 1..62 in pairs (1,2)...(61,62), then event 63 as epilogue
            #pragma unroll
            for (int k = 1; k < SEG - 1; k += 2) {
                { float ek = e[k];   S = fmaf(S, ek, ek); lsum1 += __logf(fmaf(ab, S, mu)); }
                { float ek = e[k+1]; S = fmaf(S, ek, ek); lsum0 += __logf(fmaf(ab, S, mu)); }
            }
            { float ek = e[SEG-1]; S = fmaf(S, ek, ek); lsum1 += __logf(fmaf(ab, S, mu)); }
        } else {
            float tprev = ts[start];
            lsum0 += __logf(fmaf(ab, S, mu));
            for (int j = start + 1; j < end; ++j) {
                float t = ts[j];
                float ee = __expf(-beta * (t - tprev));
                S = fmaf(S, ee, ee);
                lsum0 += __logf(fmaf(ab, S, mu));
                tprev = t;
            }
        }
    }
    float lsum = lsum0 + lsum1;
    #pragma unroll
    for (int off = 32; off > 0; off >>= 1) lsum += __shfl_down(lsum, off);
    __shared__ float wsum[TPB / 64];
    if (lane == 0) wsum[wave] = lsum;
    __syncthreads();
    if (tid == 0) {
        float tot = 0.f;
        #pragma unroll
        for (int w = 0; w < TPB / 64; ++w) tot += wsum[w];
        blkSum[blockIdx.x] = (double)tot;
    }
    __threadfence();
    grid.sync();

    // ---------------- stage 5: final assembly ------------------------------------
    if (blockIdx.x == 0) {
        double v = (tid < NB) ? blkSum[tid] : 0.0;
        #pragma unroll
        for (int off = 32; off > 0; off >>= 1) v += __shfl_down(v, off);
        __shared__ double dsum[TPB / 64];
        if (lane == 0) dsum[wave] = v;
        __syncthreads();
        if (tid == 0) {
            double tot = 0.0;
            #pragma unroll
            for (int w = 0; w < TPB / 64; ++w) tot += dsum[w];
            const float integral = mu * Tf + (alpha / beta) * ((float)N - stats[0]);
            out[0] = (float)(tot - (double)integral);
        }
    }
}

extern "C" void kernel_launch(void* const* d_in, const int* in_sizes, int n_in,
                              void* d_out, int out_size, void* d_ws, size_t ws_size,
                              hipStream_t stream) {
    const float* ts = (const float*)d_in[0];
    const float* mu = (const float*)d_in[1];
    const float* la = (const float*)d_in[2];
    const float* lb = (const float*)d_in[3];
    const int*   T  = (const int*)d_in[4];
    int N = in_sizes[0];
    int NSEG = (N + SEG - 1) / SEG;
    int NB = (NSEG + TPB - 1) / TPB;

    char* w = (char*)d_ws;
    double* blkSum   = (double*)w;                          // NB * 8
    DA*     blkDA    = (DA*)(w + (size_t)NB * 8);           // NB * 8
    float*  blkCarry = (float*)(w + (size_t)NB * 16);       // NB * 4
    float*  stats    = (float*)(w + (size_t)NB * 20);       // 4
    float*  out      = (float*)d_out;

    void* args[] = { (void*)&ts, (void*)&mu, (void*)&la, (void*)&lb, (void*)&T,
                     (void*)&N, (void*)&NSEG, (void*)&NB,
                     (void*)&blkDA, (void*)&blkCarry, (void*)&blkSum,
                     (void*)&stats, (void*)&out };
    hipLaunchCooperativeKernel((const void*)hawkes_fused, dim3(NB), dim3(TPB),
                               args, 0, stream);
}

// Round 4
// 100.080 us; speedup vs baseline: 2.0235x; 2.0235x over previous
//
#include <hip/hip_runtime.h>

#define SEG 16
#define TPB 256

struct DA { float d, a; };

__device__ __forceinline__ DA da_compose(DA f, DA g) {
    // apply f first, then g:  c -> (c*f.d + f.a)*g.d + g.a
    DA r; r.d = f.d * g.d; r.a = fmaf(f.a, g.d, g.a); return r;
}

// ---------- K1: per-thread segment (D,A) -> block aggregate; init acc/ticket ----------
__global__ void __launch_bounds__(TPB) hawkes_k1(
    const float* __restrict__ ts, const float* __restrict__ lb_p,
    const int* __restrict__ T_p, int N, int NSEG,
    DA* __restrict__ blkDA, double* __restrict__ acc, unsigned* __restrict__ ticket)
{
    const float beta = __expf(*lb_p);
    const float Tf = (float)(*T_p);
    const int tid = threadIdx.x;
    const int g = blockIdx.x * TPB + tid;
    const int lane = tid & 63, wave = tid >> 6;

    if (blockIdx.x == 0 && tid == 0) { *acc = 0.0; *ticket = 0u; }

    DA my; my.d = 1.f; my.a = 0.f;
    if (g < NSEG) {
        const int start = g * SEG;
        const int end = min(start + SEG, N);
        float R = 1.f, t0, tlast;
        if (end == start + SEG) {
            const float4* p = (const float4*)(ts + start);
            float4 a = p[0], b = p[1], c = p[2], d = p[3];
            t0 = a.x;
            float tp = a.x;
#define K1S(tt) { R = fmaf(R, __expf(-beta * ((tt) - tp)), 1.f); tp = (tt); }
            K1S(a.y) K1S(a.z) K1S(a.w)
            K1S(b.x) K1S(b.y) K1S(b.z) K1S(b.w)
            K1S(c.x) K1S(c.y) K1S(c.z) K1S(c.w)
            K1S(d.x) K1S(d.y) K1S(d.z) K1S(d.w)
#undef K1S
            tlast = d.w;
        } else {
            t0 = ts[start]; tlast = t0;
            for (int j = start + 1; j < end; ++j) {
                float t = ts[j];
                R = fmaf(R, __expf(-beta * (t - tlast)), 1.f); tlast = t;
            }
        }
        const float rnext = (end < N) ? ts[end] : Tf;
        my.a = R * __expf(-beta * (rnext - tlast));
        my.d = __expf(-beta * (rnext - t0));
    }

    // wave inclusive scan, then compose the 4 wave aggregates in order
    DA inc = my;
    #pragma unroll
    for (int off = 1; off < 64; off <<= 1) {
        DA up; up.d = __shfl_up(inc.d, off); up.a = __shfl_up(inc.a, off);
        if (lane >= off) inc = da_compose(up, inc);
    }
    __shared__ DA wagg[TPB / 64];
    if (lane == 63) wagg[wave] = inc;
    __syncthreads();
    if (tid == 0) {
        DA aggr = wagg[0];
        #pragma unroll
        for (int w = 1; w < TPB / 64; ++w) aggr = da_compose(aggr, wagg[w]);
        blkDA[blockIdx.x] = aggr;
    }
}

// ---------- K2: redundant global carry scan + per-event eval + ticketed finish ----------
__global__ void __launch_bounds__(TPB) hawkes_k2(
    const float* __restrict__ ts,
    const float* __restrict__ mu_p, const float* __restrict__ la_p,
    const float* __restrict__ lb_p, const int* __restrict__ T_p,
    int N, int NSEG, int NB,
    const DA* __restrict__ blkDA, double* __restrict__ acc,
    unsigned* __restrict__ ticket, float* __restrict__ out)
{
    const float beta  = __expf(*lb_p);
    const float mu    = *mu_p;
    const float alpha = __expf(*la_p);
    const float ab    = alpha * beta;
    const float Tf    = (float)(*T_p);
    const int tid = threadIdx.x;
    const int g = blockIdx.x * TPB + tid;
    const int lane = tid & 63, wave = tid >> 6;

    // ---- stage 1: recompute my segment (D,A); keep decay factors in registers ----
    float e[SEG];
    DA my; my.d = 1.f; my.a = 0.f;
    bool full = false;
    const int start = g * SEG;
    const int end = (g < NSEG) ? min(start + SEG, N) : start;
    if (g < NSEG) {
        full = (end == start + SEG);
        float R = 1.f, t0, tlast;
        if (full) {
            const float4* p = (const float4*)(ts + start);
            float4 a = p[0], b = p[1], c = p[2], d = p[3];
            t0 = a.x;
            e[1]  = __expf(-beta * (a.y - a.x));
            e[2]  = __expf(-beta * (a.z - a.y));
            e[3]  = __expf(-beta * (a.w - a.z));
            e[4]  = __expf(-beta * (b.x - a.w));
            e[5]  = __expf(-beta * (b.y - b.x));
            e[6]  = __expf(-beta * (b.z - b.y));
            e[7]  = __expf(-beta * (b.w - b.z));
            e[8]  = __expf(-beta * (c.x - b.w));
            e[9]  = __expf(-beta * (c.y - c.x));
            e[10] = __expf(-beta * (c.z - c.y));
            e[11] = __expf(-beta * (c.w - c.z));
            e[12] = __expf(-beta * (d.x - c.w));
            e[13] = __expf(-beta * (d.y - d.x));
            e[14] = __expf(-beta * (d.z - d.y));
            e[15] = __expf(-beta * (d.w - d.z));
            #pragma unroll
            for (int k = 1; k < SEG; ++k) R = fmaf(R, e[k], 1.f);
            tlast = d.w;
        } else {
            t0 = ts[start]; tlast = t0;
            for (int j = start + 1; j < end; ++j) {
                float t = ts[j];
                R = fmaf(R, __expf(-beta * (t - tlast)), 1.f); tlast = t;
            }
        }
        const float rnext = (end < N) ? ts[end] : Tf;
        my.a = R * __expf(-beta * (rnext - tlast));
        my.d = __expf(-beta * (rnext - t0));
    }

    // ---- stage 2: block-local exclusive scan (per-thread prefix within block) ----
    DA inc = my;
    #pragma unroll
    for (int off = 1; off < 64; off <<= 1) {
        DA up; up.d = __shfl_up(inc.d, off); up.a = __shfl_up(inc.a, off);
        if (lane >= off) inc = da_compose(up, inc);
    }
    __shared__ DA wagg[TPB / 64];
    if (lane == 63) wagg[wave] = inc;
    __syncthreads();
    DA pre; pre.d = 1.f; pre.a = 0.f;
    for (int w = 0; w < wave; ++w) pre = da_compose(pre, wagg[w]);
    DA lexcl; lexcl.d = __shfl_up(inc.d, 1); lexcl.a = __shfl_up(inc.a, 1);
    if (lane == 0) { lexcl.d = 1.f; lexcl.a = 0.f; }
    DA excl = da_compose(pre, lexcl);

    // ---- stage 3: block-parallel scan of ALL block aggregates (redundant per block) ----
    const int CH = (NB + TPB - 1) / TPB;   // blocks per thread chunk
    DA comp; comp.d = 1.f; comp.a = 0.f;
    for (int j = 0; j < CH; ++j) {
        const int idx = tid * CH + j;
        if (idx < NB) comp = da_compose(comp, blkDA[idx]);
    }
    DA inc2 = comp;
    #pragma unroll
    for (int off = 1; off < 64; off <<= 1) {
        DA up; up.d = __shfl_up(inc2.d, off); up.a = __shfl_up(inc2.a, off);
        if (lane >= off) inc2 = da_compose(up, inc2);
    }
    __shared__ DA wagg2[TPB / 64];
    if (lane == 63) wagg2[wave] = inc2;
    __syncthreads();
    DA pre2; pre2.d = 1.f; pre2.a = 0.f;
    for (int w = 0; w < wave; ++w) pre2 = da_compose(pre2, wagg2[w]);
    DA lex2; lex2.d = __shfl_up(inc2.d, 1); lex2.a = __shfl_up(inc2.a, 1);
    if (lane == 0) { lex2.d = 1.f; lex2.a = 0.f; }
    DA chunkExcl = da_compose(pre2, lex2);

    __shared__ DA exclArr[TPB];
    __shared__ DA totalSh;
    exclArr[tid] = chunkExcl;
    if (tid == TPB - 1) totalSh = da_compose(pre2, inc2);   // full composition -> S(T)
    __syncthreads();

    const int b = blockIdx.x;
    const int c0 = b / CH, pp = b - c0 * CH;
    DA E = exclArr[c0];
    for (int j = 0; j < pp; ++j) E = da_compose(E, blkDA[c0 * CH + j]);
    const float carry = E.a;            // global decayed sum entering this block
    const float S_T = totalSh.a;        // decayed sum at time T

    // ---- stage 4: per-event intensities from register-resident e[] ----
    float S = fmaf(carry, excl.d, excl.a);
    float lsum = 0.f;
    if (g < NSEG) {
        if (full) {
            lsum += __logf(fmaf(ab, S, mu));
            #pragma unroll
            for (int k = 1; k < SEG; ++k) {
                float ek = e[k];
                S = fmaf(S, ek, ek);
                lsum += __logf(fmaf(ab, S, mu));
            }
        } else {
            float tprev = ts[start];
            lsum += __logf(fmaf(ab, S, mu));
            for (int j = start + 1; j < end; ++j) {
                float t = ts[j];
                float ee = __expf(-beta * (t - tprev));
                S = fmaf(S, ee, ee);
                lsum += __logf(fmaf(ab, S, mu));
                tprev = t;
            }
        }
    }

    // ---- stage 5: block reduce -> device accumulator; last block assembles out ----
    #pragma unroll
    for (int off = 32; off > 0; off >>= 1) lsum += __shfl_down(lsum, off);
    __shared__ float wsum[TPB / 64];
    if (lane == 0) wsum[wave] = lsum;
    __syncthreads();
    if (tid == 0) {
        float tot = 0.f;
        #pragma unroll
        for (int w = 0; w < TPB / 64; ++w) tot += wsum[w];
        atomicAdd(acc, (double)tot);
        __threadfence();
        unsigned old = atomicAdd(ticket, 1u);
        if (old == (unsigned)(NB - 1)) {
            __threadfence();
            double tt = atomicAdd(acc, 0.0);  // coherent read of final sum
            const float integral = mu * Tf + (alpha / beta) * ((float)N - S_T);
            out[0] = (float)(tt - (double)integral);
        }
    }
}

extern "C" void kernel_launch(void* const* d_in, const int* in_sizes, int n_in,
                              void* d_out, int out_size, void* d_ws, size_t ws_size,
                              hipStream_t stream) {
    const float* ts = (const float*)d_in[0];
    const float* mu = (const float*)d_in[1];
    const float* la = (const float*)d_in[2];
    const float* lb = (const float*)d_in[3];
    const int*   T  = (const int*)d_in[4];
    const int N = in_sizes[0];
    const int NSEG = (N + SEG - 1) / SEG;
    const int NB = (NSEG + TPB - 1) / TPB;

    char* w = (char*)d_ws;
    double*   acc    = (double*)w;            // 8 B
    unsigned* ticket = (unsigned*)(w + 8);    // 4 B (+4 pad)
    DA*       blkDA  = (DA*)(w + 16);         // NB * 8 B

    hawkes_k1<<<NB, TPB, 0, stream>>>(ts, lb, T, N, NSEG, blkDA, acc, ticket);
    hawkes_k2<<<NB, TPB, 0, stream>>>(ts, mu, la, lb, T, N, NSEG, NB, blkDA, acc, ticket,
                                      (float*)d_out);
}